// Round 2
// baseline (234.218 us; speedup 1.0000x reference)
//
#include <hip/hip_runtime.h>

#define NB 64
#define ZDIM 128
#define NCOEF 1025
#define NFR 128
#define COLS 131200          /* NCOEF*NFR */
#define WINSZ 2048
#define HALFW 1024
#define NSAMP 131072
#define IMPN 4096

// workspace layout in floats
#define TF_OFF   0
#define TF_SZ    (NB*COLS)                  /* 8,396,800 */
#define CUR_OFF  (TF_OFF + TF_SZ)
#define CUR_SZ   (NB*4*NCOEF*2)             /* 524,800 */
#define SPEC_OFF (CUR_OFF + CUR_SZ)
#define SPEC_SZ  (NB*NFR*NCOEF*2)           /* 16,793,600 */
#define WINT_OFF (SPEC_OFF + SPEC_SZ)
#define WINT_SZ  (WINSZ)
#define TW_OFF   (WINT_OFF + WINT_SZ)
#define TW_SZ    (HALFW*2)

// ---------------------------------------------------------------- init tables
__global__ __launch_bounds__(256) void init_tables(float* __restrict__ winT,
                                                   float2* __restrict__ twG) {
  int i = blockIdx.x * 256 + threadIdx.x;
  if (i < WINSZ) {
    // periodic hann
    winT[i] = 0.5f - 0.5f * cosf((float)(2.0 * 3.14159265358979323846 / 2048.0) * (float)i);
  }
  if (i < HALFW) {
    // forward twiddle e^{-2*pi*i*m/2048}
    float ang = (float)(-2.0 * 3.14159265358979323846 / 2048.0) * (float)i;
    float sv, cv;
    sincosf(ang, &sv, &cv);
    twG[i] = make_float2(cv, sv);
  }
}

// ---------------------------------------------------------------- GEMM + squash
__global__ __launch_bounds__(256) void tf_gemm_kernel(const float* __restrict__ z,
                                                      const float* __restrict__ W,
                                                      const float* __restrict__ bias,
                                                      float* __restrict__ tf) {
  __shared__ float4 zs[NB * (ZDIM / 4)];  // 64*32 float4 = 32 KB
  int tid = threadIdx.x;
  for (int i = tid; i < NB * (ZDIM / 4); i += 256)
    zs[i] = reinterpret_cast<const float4*>(z)[i];
  __syncthreads();

  int col = blockIdx.x * 256 + tid;
  if (col >= COLS) return;

  float bv = bias[col];
  float acc[NB];
#pragma unroll
  for (int b = 0; b < NB; ++b) acc[b] = bv;

  for (int zq = 0; zq < ZDIM / 4; ++zq) {
    float w0 = W[(size_t)(4 * zq + 0) * COLS + col];
    float w1 = W[(size_t)(4 * zq + 1) * COLS + col];
    float w2 = W[(size_t)(4 * zq + 2) * COLS + col];
    float w3 = W[(size_t)(4 * zq + 3) * COLS + col];
#pragma unroll
    for (int b = 0; b < NB; ++b) {
      float4 zv = zs[b * (ZDIM / 4) + zq];
      acc[b] = fmaf(zv.x, w0, fmaf(zv.y, w1, fmaf(zv.z, w2, fmaf(zv.w, w3, acc[b]))));
    }
  }

  const float RESR = (1.0f - 0.02f) * 0.99f;
#pragma unroll
  for (int b = 0; b < NB; ++b) {
    float sg = 1.0f / (1.0f + __expf(-acc[b]));
    tf[(size_t)b * COLS + col] = 0.02f + sg * RESR;
  }
}

// ---------------------------------------------------------------- full 2048 FFT (fwd only)
static __device__ __forceinline__ void wg_fft2048(float* ar, float* ai,
                                                  float* br, float* bi,
                                                  const float2* tw,
                                                  float** outr, float** outi) {
  float *xr = ar, *xi = ai, *yr = br, *yi = bi;
  int m = 1;
  for (int s = 0; s < 11; ++s) {
    __syncthreads();
#pragma unroll
    for (int it = 0; it < 4; ++it) {
      int t = (int)threadIdx.x + it * 256;
      int jm = t & ~(m - 1);
      float x0r = xr[t], x0i = xi[t];
      float x1r = xr[t + 1024], x1i = xi[t + 1024];
      float2 w = tw[jm];
      float sr = x0r + x1r, si = x0i + x1i;
      float dr = x0r - x1r, di = x0i - x1i;
      float pr = dr * w.x - di * w.y;
      float pi = dr * w.y + di * w.x;
      yr[t + jm] = sr;      yi[t + jm] = si;
      yr[t + jm + m] = pr;  yi[t + jm + m] = pi;
    }
    float* t0 = xr; xr = yr; yr = t0;
    float* t1 = xi; xi = yi; yi = t1;
    m <<= 1;
  }
  __syncthreads();
  *outr = xr; *outi = xi;
}

// ---------------------------------------------------------------- forward rfft
// grid = NB*4 (b, frame f<4). cur[(b*4+f)*1025 + k] = rfft(win * x_frame)[k]
__global__ __launch_bounds__(256) void fwd_fft_kernel(const float* __restrict__ imp,
                                                      const float* __restrict__ winT,
                                                      const float2* __restrict__ twG,
                                                      float2* __restrict__ cur) {
  __shared__ float b0r[WINSZ], b0i[WINSZ], b1r[WINSZ], b1i[WINSZ];
  __shared__ float2 tw[HALFW];
  int wg = blockIdx.x;
  int b = wg >> 2, f = wg & 3;
  int tid = threadIdx.x;

  for (int i = tid; i < HALFW; i += 256) tw[i] = twG[i];
  for (int w = tid; w < WINSZ; w += 256) {
    int s = f * HALFW + w;
    float v = (s < IMPN) ? imp[(size_t)b * IMPN + s] * winT[w] : 0.0f;
    b0r[w] = v;
    b0i[w] = 0.0f;
  }
  float *rr, *ri;
  wg_fft2048(b0r, b0i, b1r, b1i, tw, &rr, &ri);
  for (int k = tid; k < NCOEF; k += 256)
    cur[(size_t)wg * NCOEF + k] = make_float2(rr[k], ri[k]);
}

// ---------------------------------------------------------------- recurrence
__global__ __launch_bounds__(256) void recur_kernel(const float* __restrict__ tf,
                                                    const float2* __restrict__ cur,
                                                    float2* __restrict__ spec) {
  int id = blockIdx.x * 256 + threadIdx.x;
  if (id >= NB * NCOEF) return;
  int b = id / NCOEF;
  int k = id - b * NCOEF;

  float g = 3.14159265358979323846f * (float)k / 1024.0f;
  float sg, cg;
  sincosf(g, &sg, &cg);
  bool herm = (k == 0) || (k == HALFW);

  const float* tfr = tf + (size_t)b * COLS + (size_t)k * NFR;
  const float2* curb = cur + (size_t)b * 4 * NCOEF + k;
  float2* specb = spec + (size_t)b * NFR * NCOEF + k;

  float pre = 0.0f, pim = 0.0f;
  for (int f = 0; f < NFR; ++f) {
    float tfv = tfr[f];
    float cr = 0.0f, ci = 0.0f;
    if (f < 4) {
      float2 cv = curb[(size_t)f * NCOEF];
      cr = cv.x; ci = cv.y;
    }
    float ire = herm ? 0.0f : pim;
    float rre = fmaf(pre, cg, ire * sg);
    float rim = -fmaf(pre, sg, ire * cg);
    float sre = (cr + rre) * tfv;
    float sim = (ci + rim) * tfv;
    specb[(size_t)f * NCOEF] = make_float2(sre, sim);
    pre = sre; pim = sim;
  }
}

// ---------------------------------------------------------------- irfft + OLA (half-size)
// 2048-pt irfft via pack -> 1024-pt complex IFFT -> deinterleave.
// Xe[k]=(X[k]+conj(X[1024-k]))/2, Xo[k]=(X[k]-conj(X[1024-k]))/2 * e^{+2pi i k/2048}
// Z[k]=Xe[k]+i*Xo[k]; z=IFFT_1024(Z)/1024; x[2m]=Re z[m], x[2m+1]=Im z[m].
__global__ __launch_bounds__(256) void inv_fft_ola_kernel(const float2* __restrict__ spec,
                                                          const float* __restrict__ winT,
                                                          const float2* __restrict__ twG,
                                                          float* __restrict__ out) {
  __shared__ float ar[1040], ai[1040];   // holds X (1025), then ping-pong plane
  __shared__ float br[1024], bi[1024];
  __shared__ float2 twH[512];            // e^{+2pi i j/1024}, j<512
  int wg = blockIdx.x;
  int b = wg >> 7, f = wg & 127;
  int tid = threadIdx.x;

  for (int j = tid; j < 512; j += 256) {
    float2 t = twG[2 * j];
    twH[j] = make_float2(t.x, -t.y);
  }
  const float2* sp = spec + (size_t)wg * NCOEF;
  for (int k = tid; k < NCOEF; k += 256) {
    float2 v = sp[k];
    if (k == 0 || k == HALFW) v.y = 0.0f;  // irfft ignores Im at DC/Nyquist
    ar[k] = v.x;
    ai[k] = v.y;
  }
  __syncthreads();

  // pack Z into br/bi
#pragma unroll
  for (int it = 0; it < 4; ++it) {
    int j = tid + it * 256;
    float xjr = ar[j], xji = ai[j];
    int mj = HALFW - j;                 // j=0 -> 1024 (Nyquist)
    float xmr = ar[mj], xmi = ai[mj];
    float Xer = 0.5f * (xjr + xmr), Xei = 0.5f * (xji - xmi);
    float Xpr = 0.5f * (xjr - xmr), Xpi = 0.5f * (xji + xmi);
    float2 tg = twG[j];                 // e^{-2pi i j/2048}
    float c = tg.x, s = -tg.y;          // e^{+2pi i j/2048}
    float Xor_ = Xpr * c - Xpi * s;
    float Xoi_ = Xpr * s + Xpi * c;
    br[j] = Xer - Xoi_;
    bi[j] = Xei + Xor_;
  }

  // Stockham 1024-pt IFFT (twiddles already conjugated in twH)
  float *xr = br, *xi = bi, *yr = ar, *yi = ai;
  int m = 1;
  for (int s = 0; s < 10; ++s) {
    __syncthreads();
#pragma unroll
    for (int it = 0; it < 2; ++it) {
      int t = tid + it * 256;
      int jm = t & ~(m - 1);
      float x0r = xr[t], x0i = xi[t];
      float x1r = xr[t + 512], x1i = xi[t + 512];
      float2 w = twH[jm];
      float sr = x0r + x1r, si = x0i + x1i;
      float dr = x0r - x1r, di = x0i - x1i;
      float pr = dr * w.x - di * w.y;
      float pi = dr * w.y + di * w.x;
      yr[t + jm] = sr;      yi[t + jm] = si;
      yr[t + jm + m] = pr;  yi[t + jm + m] = pi;
    }
    float* q0 = xr; xr = yr; yr = q0;
    float* q1 = xi; xi = yi; yi = q1;
    m <<= 1;
  }
  __syncthreads();

  // deinterleave + window + overlap-add
  const float inv_n = 1.0f / 1024.0f;
  int base = f * HALFW;
  const float2* win2 = (const float2*)winT;
  float* ob = out + (size_t)b * NSAMP;
#pragma unroll
  for (int it = 0; it < 4; ++it) {
    int mI = tid + it * 256;
    float2 wv = win2[mI];
    int p0 = base + 2 * mI;
    float ev = xr[mI] * inv_n * wv.x;
    float ov = xi[mI] * inv_n * wv.y;
    if (p0 < NSAMP)     atomicAdd(ob + p0, ev);
    if (p0 + 1 < NSAMP) atomicAdd(ob + p0 + 1, ov);
  }
}

// ---------------------------------------------------------------- launch
extern "C" void kernel_launch(void* const* d_in, const int* in_sizes, int n_in,
                              void* d_out, int out_size, void* d_ws, size_t ws_size,
                              hipStream_t stream) {
  const float* z    = (const float*)d_in[0];   // 64*1*128
  const float* imp  = (const float*)d_in[1];   // 64*1*4096
  const float* W    = (const float*)d_in[2];   // 128*131200
  const float* bias = (const float*)d_in[3];   // 131200

  float* ws = (float*)d_ws;
  float*  tf   = ws + TF_OFF;
  float2* cur  = (float2*)(ws + CUR_OFF);
  float2* spec = (float2*)(ws + SPEC_OFF);
  float*  winT = ws + WINT_OFF;
  float2* twG  = (float2*)(ws + TW_OFF);
  float*  out  = (float*)d_out;

  hipMemsetAsync(out, 0, (size_t)out_size * sizeof(float), stream);

  init_tables<<<8, 256, 0, stream>>>(winT, twG);
  tf_gemm_kernel<<<(COLS + 255) / 256, 256, 0, stream>>>(z, W, bias, tf);
  fwd_fft_kernel<<<NB * 4, 256, 0, stream>>>(imp, winT, twG, cur);
  recur_kernel<<<(NB * NCOEF + 255) / 256, 256, 0, stream>>>(tf, cur, spec);
  inv_fft_ola_kernel<<<NB * NFR, 256, 0, stream>>>(spec, winT, twG, out);
}

// Round 3
// 167.408 us; speedup vs baseline: 1.3991x; 1.3991x over previous
//
#include <hip/hip_runtime.h>

#define NB 64
#define ZDIM 128
#define NCOEF 1025
#define NFR 128
#define COLS 131200          /* NCOEF*NFR */
#define WINSZ 2048
#define HALFW 1024
#define NSAMP 131072
#define IMPN 4096

// workspace layout in floats
#define TF_OFF   0
#define TF_SZ    (NB*COLS)                  /* 8,396,800 */
#define CUR_OFF  (TF_OFF + TF_SZ)
#define CUR_SZ   (NB*4*NCOEF*2)             /* 524,800 */
#define SPEC_OFF (CUR_OFF + CUR_SZ)
#define SPEC_SZ  (NB*NFR*NCOEF*2)           /* 16,793,600 */
#define WINT_OFF (SPEC_OFF + SPEC_SZ)
#define WINT_SZ  (WINSZ)
#define TW_OFF   (WINT_OFF + WINT_SZ)
#define TW_SZ    (HALFW*2)

// XOR swizzle: bijective involution on [0,1024); keeps stride-1 reads
// conflict-free and reduces radix-4 scatter writes to <=2-way.
#define PHYS(i) ((i) ^ (((i) >> 5) & 3))

// ---------------------------------------------------------------- init tables
__global__ __launch_bounds__(256) void init_tables(float* __restrict__ winT,
                                                   float2* __restrict__ twG) {
  int i = blockIdx.x * 256 + threadIdx.x;
  if (i < WINSZ) {
    winT[i] = 0.5f - 0.5f * cosf((float)(2.0 * 3.14159265358979323846 / 2048.0) * (float)i);
  }
  if (i < HALFW) {
    float ang = (float)(-2.0 * 3.14159265358979323846 / 2048.0) * (float)i;
    float sv, cv;
    sincosf(ang, &sv, &cv);
    twG[i] = make_float2(cv, sv);
  }
}

// ---------------------------------------------------------------- GEMM + squash
__global__ __launch_bounds__(256) void tf_gemm_kernel(const float* __restrict__ z,
                                                      const float* __restrict__ W,
                                                      const float* __restrict__ bias,
                                                      float* __restrict__ tf) {
  __shared__ float4 zs[NB * (ZDIM / 4)];  // 32 KB
  int tid = threadIdx.x;
  for (int i = tid; i < NB * (ZDIM / 4); i += 256)
    zs[i] = reinterpret_cast<const float4*>(z)[i];
  __syncthreads();

  int col = blockIdx.x * 256 + tid;
  if (col >= COLS) return;

  float bv = bias[col];
  float acc[NB];
#pragma unroll
  for (int b = 0; b < NB; ++b) acc[b] = bv;

  for (int zq = 0; zq < ZDIM / 4; ++zq) {
    float w0 = W[(size_t)(4 * zq + 0) * COLS + col];
    float w1 = W[(size_t)(4 * zq + 1) * COLS + col];
    float w2 = W[(size_t)(4 * zq + 2) * COLS + col];
    float w3 = W[(size_t)(4 * zq + 3) * COLS + col];
#pragma unroll
    for (int b = 0; b < NB; ++b) {
      float4 zv = zs[b * (ZDIM / 4) + zq];
      acc[b] = fmaf(zv.x, w0, fmaf(zv.y, w1, fmaf(zv.z, w2, fmaf(zv.w, w3, acc[b]))));
    }
  }

  const float RESR = (1.0f - 0.02f) * 0.99f;
#pragma unroll
  for (int b = 0; b < NB; ++b) {
    float sg = 1.0f / (1.0f + __expf(-acc[b]));
    tf[(size_t)b * COLS + col] = 0.02f + sg * RESR;
  }
}

// ---------------------------------------------------------------- fwd 2048 FFT (radix-2, unchanged)
static __device__ __forceinline__ void wg_fft2048(float* ar, float* ai,
                                                  float* br, float* bi,
                                                  const float2* tw,
                                                  float** outr, float** outi) {
  float *xr = ar, *xi = ai, *yr = br, *yi = bi;
  int m = 1;
  for (int s = 0; s < 11; ++s) {
    __syncthreads();
#pragma unroll
    for (int it = 0; it < 4; ++it) {
      int t = (int)threadIdx.x + it * 256;
      int jm = t & ~(m - 1);
      float x0r = xr[t], x0i = xi[t];
      float x1r = xr[t + 1024], x1i = xi[t + 1024];
      float2 w = tw[jm];
      float sr = x0r + x1r, si = x0i + x1i;
      float dr = x0r - x1r, di = x0i - x1i;
      float pr = dr * w.x - di * w.y;
      float pi = dr * w.y + di * w.x;
      yr[t + jm] = sr;      yi[t + jm] = si;
      yr[t + jm + m] = pr;  yi[t + jm + m] = pi;
    }
    float* t0 = xr; xr = yr; yr = t0;
    float* t1 = xi; xi = yi; yi = t1;
    m <<= 1;
  }
  __syncthreads();
  *outr = xr; *outi = xi;
}

__global__ __launch_bounds__(256) void fwd_fft_kernel(const float* __restrict__ imp,
                                                      const float* __restrict__ winT,
                                                      const float2* __restrict__ twG,
                                                      float2* __restrict__ cur) {
  __shared__ float b0r[WINSZ], b0i[WINSZ], b1r[WINSZ], b1i[WINSZ];
  __shared__ float2 tw[HALFW];
  int wg = blockIdx.x;
  int b = wg >> 2, f = wg & 3;
  int tid = threadIdx.x;

  for (int i = tid; i < HALFW; i += 256) tw[i] = twG[i];
  for (int w = tid; w < WINSZ; w += 256) {
    int s = f * HALFW + w;
    float v = (s < IMPN) ? imp[(size_t)b * IMPN + s] * winT[w] : 0.0f;
    b0r[w] = v;
    b0i[w] = 0.0f;
  }
  float *rr, *ri;
  wg_fft2048(b0r, b0i, b1r, b1i, tw, &rr, &ri);
  for (int k = tid; k < NCOEF; k += 256)
    cur[(size_t)wg * NCOEF + k] = make_float2(rr[k], ri[k]);
}

// ---------------------------------------------------------------- recurrence
__global__ __launch_bounds__(256) void recur_kernel(const float* __restrict__ tf,
                                                    const float2* __restrict__ cur,
                                                    float2* __restrict__ spec) {
  int id = blockIdx.x * 256 + threadIdx.x;
  if (id >= NB * NCOEF) return;
  int b = id / NCOEF;
  int k = id - b * NCOEF;

  float g = 3.14159265358979323846f * (float)k / 1024.0f;
  float sg, cg;
  sincosf(g, &sg, &cg);
  bool herm = (k == 0) || (k == HALFW);

  const float4* tf4 = (const float4*)(tf + (size_t)b * COLS + (size_t)k * NFR);
  const float2* curb = cur + (size_t)b * 4 * NCOEF + k;
  float2* specb = spec + (size_t)b * NFR * NCOEF + k;

  float pre = 0.0f, pim = 0.0f;
#pragma unroll 2
  for (int f4 = 0; f4 < NFR / 4; ++f4) {
    float4 tv = tf4[f4];
    float tfs[4] = {tv.x, tv.y, tv.z, tv.w};
#pragma unroll
    for (int u = 0; u < 4; ++u) {
      int f = 4 * f4 + u;
      float tfv = tfs[u];
      float cr = 0.0f, ci = 0.0f;
      if (f < 4) {
        float2 cv = curb[(size_t)f * NCOEF];
        cr = cv.x; ci = cv.y;
      }
      float ire = herm ? 0.0f : pim;
      float rre = fmaf(pre, cg, ire * sg);
      float rim = -fmaf(pre, sg, ire * cg);
      float sre = (cr + rre) * tfv;
      float sim = (ci + rim) * tfv;
      specb[(size_t)f * NCOEF] = make_float2(sre, sim);
      pre = sre; pim = sim;
    }
  }
}

// ---------------------------------------------------------------- dual irfft + OLA (no atomics)
// Block (b,j) owns out[b, j*1024 .. j*1024+1023]:
//   out = irfft(spec[b][j])[0:1024)*win[0:1024) + irfft(spec[b][j-1])[1024:2048)*win[1024:2048)
// irfft2048 = pack to Z(1024) -> conj -> fwd radix-4 FFT1024 -> conj -> deinterleave.
__global__ __launch_bounds__(256) void inv_fft_ola_kernel(const float2* __restrict__ spec,
                                                          const float* __restrict__ winT,
                                                          const float2* __restrict__ twG,
                                                          float* __restrict__ out) {
  __shared__ float L[8][1024];   // planes: 0..3 ping (q0r,q0i,q1r,q1i), 4..7 pong
  __shared__ float2 twL[256];    // e^{-2pi i j/1024}, j<256
  __shared__ float nyq[2];

  int wg = blockIdx.x;
  int b = wg >> 7, jfr = wg & 127;
  int tid = threadIdx.x;

  if (tid < 256) twL[tid] = twG[2 * tid];

  // ---- load X (frames j and j-1) into pong planes 4..7
  const float2* spA = spec + ((size_t)b * NFR + jfr) * NCOEF;
  const float2* spB = spec + ((size_t)b * NFR + (jfr > 0 ? jfr - 1 : 0)) * NCOEF;
#pragma unroll
  for (int it = 0; it < 4; ++it) {
    int k = tid + it * 256;
    float2 v = spA[k];
    float2 u = spB[k];
    if (k == 0) { v.y = 0.0f; u.y = 0.0f; }   // irfft drops Im at DC
    int pk = PHYS(k);
    L[4][pk] = v.x; L[5][pk] = v.y;
    L[6][pk] = u.x; L[7][pk] = u.y;
  }
  if (tid == 0) {
    nyq[0] = spA[HALFW].x;                    // Nyquist (Im dropped)
    nyq[1] = spB[HALFW].x;
  }
  __syncthreads();

  // ---- pack Z = Xe + i*Xo, then conjugate (inverse via forward FFT)
#pragma unroll
  for (int it = 0; it < 4; ++it) {
    int j = tid + it * 256;
    float2 tg = twG[j];                       // e^{-2pi i j/2048}
    float c = tg.x, sn = -tg.y;               // e^{+2pi i j/2048}
    int pj = PHYS(j);
    int pm = PHYS((HALFW - j) & 1023);        // j=0 handled via nyq
#pragma unroll
    for (int q = 0; q < 2; ++q) {
      float xjr = L[4 + 2 * q][pj], xji = L[5 + 2 * q][pj];
      float xmr, xmi;
      if (j == 0) { xmr = nyq[q]; xmi = 0.0f; }
      else        { xmr = L[4 + 2 * q][pm]; xmi = L[5 + 2 * q][pm]; }
      float Xer = 0.5f * (xjr + xmr), Xei = 0.5f * (xji - xmi);
      float Xpr = 0.5f * (xjr - xmr), Xpi = 0.5f * (xji + xmi);
      float Xor_ = Xpr * c - Xpi * sn;
      float Xoi_ = Xpr * sn + Xpi * c;
      L[0 + 2 * q][pj] = Xer - Xoi_;
      L[1 + 2 * q][pj] = -(Xei + Xor_);       // conj
    }
  }

  // ---- forward radix-4 Stockham FFT (1024 = 4^5), dual interleaved
  int t = tid;
#pragma unroll
  for (int st = 0; st < 5; ++st) {
    __syncthreads();
    int s2 = 2 * st;
    int s = 1 << s2;
    int q = t & (s - 1);
    int j = t & ~(s - 1);                     // p*s, twiddle index
    float2 w1 = twL[j];
    float w1x = w1.x, w1y = w1.y;
    float w2x = w1x * w1x - w1y * w1y, w2y = 2.0f * w1x * w1y;
    float w3x = w2x * w1x - w2y * w1y, w3y = w2x * w1y + w2y * w1x;
    int i0 = PHYS(t), i1 = PHYS(t + 256), i2 = PHYS(t + 512), i3 = PHYS(t + 768);
    int wb = (j << 2) + q;
    int o0 = PHYS(wb), o1 = PHYS(wb + s), o2 = PHYS(wb + 2 * s), o3 = PHYS(wb + 3 * s);
    const float* xr;
    const float* xi;
    float* yr;
    float* yi;
#pragma unroll
    for (int qq = 0; qq < 2; ++qq) {
      if (st & 1) { xr = L[4 + 2 * qq]; xi = L[5 + 2 * qq]; yr = L[0 + 2 * qq]; yi = L[1 + 2 * qq]; }
      else        { xr = L[0 + 2 * qq]; xi = L[1 + 2 * qq]; yr = L[4 + 2 * qq]; yi = L[5 + 2 * qq]; }
      float ar_ = xr[i0], ai_ = xi[i0];
      float br_ = xr[i1], bi_ = xi[i1];
      float cr_ = xr[i2], ci_ = xi[i2];
      float dr_ = xr[i3], di_ = xi[i3];
      float apcr = ar_ + cr_, apci = ai_ + ci_;
      float amcr = ar_ - cr_, amci = ai_ - ci_;
      float bpdr = br_ + dr_, bpdi = bi_ + di_;
      float bmdr = br_ - dr_, bmdi = bi_ - di_;
      yr[o0] = apcr + bpdr;             yi[o0] = apci + bpdi;
      float t1r = amcr + bmdi, t1i = amci - bmdr;        // amc - i*bmd
      yr[o1] = t1r * w1x - t1i * w1y;   yi[o1] = t1r * w1y + t1i * w1x;
      float t2r = apcr - bpdr, t2i = apci - bpdi;
      yr[o2] = t2r * w2x - t2i * w2y;   yi[o2] = t2r * w2y + t2i * w2x;
      float t3r = amcr - bmdi, t3i = amci + bmdr;        // amc + i*bmd
      yr[o3] = t3r * w3x - t3i * w3y;   yi[o3] = t3r * w3y + t3i * w3x;
    }
  }
  __syncthreads();
  // 5 stages (odd) -> result in pong planes 4..7.

  // ---- deinterleave + window + direct store (x[2m]=Re/1024, x[2m+1]=-Im/1024)
  const float scale = 1.0f / 1024.0f;
  const float sc2 = (jfr > 0) ? scale : 0.0f;
  float2* ob = (float2*)(out + (size_t)b * NSAMP + (size_t)jfr * 1024);
  const float2* w2p = (const float2*)winT;
#pragma unroll
  for (int it = 0; it < 2; ++it) {
    int mI = tid + it * 256;                  // [0,512)
    float2 wva = w2p[mI];                     // win[2m], win[2m+1]
    float2 wvb = w2p[mI + 512];               // win[2m+1024], win[2m+1025]
    int pa = PHYS(mI), pb = PHYS(mI + 512);
    float e =  L[4][pa] * scale * wva.x + L[6][pb] * sc2 * wvb.x;
    float o = -L[5][pa] * scale * wva.y - L[7][pb] * sc2 * wvb.y;
    ob[mI] = make_float2(e, o);
  }
}

// ---------------------------------------------------------------- launch
extern "C" void kernel_launch(void* const* d_in, const int* in_sizes, int n_in,
                              void* d_out, int out_size, void* d_ws, size_t ws_size,
                              hipStream_t stream) {
  const float* z    = (const float*)d_in[0];
  const float* imp  = (const float*)d_in[1];
  const float* W    = (const float*)d_in[2];
  const float* bias = (const float*)d_in[3];

  float* ws = (float*)d_ws;
  float*  tf   = ws + TF_OFF;
  float2* cur  = (float2*)(ws + CUR_OFF);
  float2* spec = (float2*)(ws + SPEC_OFF);
  float*  winT = ws + WINT_OFF;
  float2* twG  = (float2*)(ws + TW_OFF);
  float*  out  = (float*)d_out;

  init_tables<<<8, 256, 0, stream>>>(winT, twG);
  tf_gemm_kernel<<<(COLS + 255) / 256, 256, 0, stream>>>(z, W, bias, tf);
  fwd_fft_kernel<<<NB * 4, 256, 0, stream>>>(imp, winT, twG, cur);
  recur_kernel<<<(NB * NCOEF + 255) / 256, 256, 0, stream>>>(tf, cur, spec);
  inv_fft_ola_kernel<<<NB * NFR, 256, 0, stream>>>(spec, winT, twG, out);
}

// Round 4
// 116.748 us; speedup vs baseline: 2.0062x; 1.4339x over previous
//
#include <hip/hip_runtime.h>

#define NB 64
#define ZDIM 128
#define NCOEF 1025
#define NFR 128
#define COLS 131200          /* NCOEF*NFR */
#define WINSZ 2048
#define HALFW 1024
#define NSAMP 131072
#define IMPN 4096

// workspace layout in floats
#define TF_OFF   0
#define TF_SZ    (NB*COLS)
#define CUR_OFF  (TF_OFF + TF_SZ)
#define CUR_SZ   (NB*4*NCOEF*2)
#define SPEC_OFF (CUR_OFF + CUR_SZ)
#define SPEC_SZ  (NB*NFR*NCOEF*2)
#define WINT_OFF (SPEC_OFF + SPEC_SZ)
#define WINT_SZ  (WINSZ)
#define TW_OFF   (WINT_OFF + WINT_SZ)
#define TW_SZ    (HALFW*2)

#define PHYS(i) ((i) ^ (((i) >> 5) & 3))

typedef short bf16x8 __attribute__((ext_vector_type(8)));
typedef float f32x4 __attribute__((ext_vector_type(4)));

// ---------------------------------------------------------------- init tables
__global__ __launch_bounds__(256) void init_tables(float* __restrict__ winT,
                                                   float2* __restrict__ twG) {
  int i = blockIdx.x * 256 + threadIdx.x;
  if (i < WINSZ) {
    winT[i] = 0.5f - 0.5f * cosf((float)(2.0 * 3.14159265358979323846 / 2048.0) * (float)i);
  }
  if (i < HALFW) {
    float ang = (float)(-2.0 * 3.14159265358979323846 / 2048.0) * (float)i;
    float sv, cv;
    sincosf(ang, &sv, &cv);
    twG[i] = make_float2(cv, sv);
  }
}

// ---------------------------------------------------------------- MFMA GEMM + squash
__device__ __forceinline__ short f2bf(float f) {
  unsigned u = __builtin_bit_cast(unsigned, f);
  u += 0x7FFFu + ((u >> 16) & 1u);      // RNE
  return (short)(u >> 16);
}

// tf[b][col] = 0.02 + sigmoid(z[b,:] . W[:,col] + bias[col]) * RESR
// grid = COLS/128 = 1025 blocks, 4 waves; wave computes 64 rows x 32 cols.
__global__ __launch_bounds__(256) void tf_gemm_mfma(const float* __restrict__ z,
                                                    const float* __restrict__ W,
                                                    const float* __restrict__ bias,
                                                    float* __restrict__ tf) {
  int tid = threadIdx.x;
  int wave = tid >> 6, lane = tid & 63;
  int colw = blockIdx.x * 128 + wave * 32;   // wave's first column
  int lr = lane & 15;                        // row-in-tile (A/C) / col-in-tile (B/C)
  int lk = (lane >> 4) * 8;                  // k-offset base for A/B frags
  int lq = (lane >> 4) * 4;                  // C row sub-offset

  // bias per n-tile (bias[col] identical across rows/regs)
  float bv[2];
#pragma unroll
  for (int n = 0; n < 2; ++n) bv[n] = bias[colw + 16 * n + lr];

  f32x4 acc[4][2];
#pragma unroll
  for (int m = 0; m < 4; ++m)
#pragma unroll
    for (int n = 0; n < 2; ++n)
      acc[m][n] = f32x4{bv[n], bv[n], bv[n], bv[n]};

#pragma unroll
  for (int s = 0; s < 4; ++s) {
    int k0 = s * 32 + lk;
    // A frags: z[16m + lr][k0 + j], j=0..7 (two float4 loads, convert)
    bf16x8 afr[4];
#pragma unroll
    for (int m = 0; m < 4; ++m) {
      const float* zp = z + (size_t)(16 * m + lr) * ZDIM + k0;
      float4 z0 = *reinterpret_cast<const float4*>(zp);
      float4 z1 = *reinterpret_cast<const float4*>(zp + 4);
      afr[m] = bf16x8{f2bf(z0.x), f2bf(z0.y), f2bf(z0.z), f2bf(z0.w),
                      f2bf(z1.x), f2bf(z1.y), f2bf(z1.z), f2bf(z1.w)};
    }
    // B frags: W[k0 + j][colw + 16n + lr]
    bf16x8 bfr[2];
#pragma unroll
    for (int n = 0; n < 2; ++n) {
      const float* wp = W + (size_t)k0 * COLS + colw + 16 * n + lr;
      bfr[n] = bf16x8{f2bf(wp[0 * (size_t)COLS]), f2bf(wp[1 * (size_t)COLS]),
                      f2bf(wp[2 * (size_t)COLS]), f2bf(wp[3 * (size_t)COLS]),
                      f2bf(wp[4 * (size_t)COLS]), f2bf(wp[5 * (size_t)COLS]),
                      f2bf(wp[6 * (size_t)COLS]), f2bf(wp[7 * (size_t)COLS])};
    }
#pragma unroll
    for (int m = 0; m < 4; ++m)
#pragma unroll
      for (int n = 0; n < 2; ++n)
        acc[m][n] = __builtin_amdgcn_mfma_f32_16x16x32_bf16(afr[m], bfr[n], acc[m][n], 0, 0, 0);
  }

  const float RESR = (1.0f - 0.02f) * 0.99f;
#pragma unroll
  for (int n = 0; n < 2; ++n) {
    int col = colw + 16 * n + lr;
#pragma unroll
    for (int m = 0; m < 4; ++m) {
      int rowb = 16 * m + lq;
#pragma unroll
      for (int r = 0; r < 4; ++r) {
        float x = acc[m][n][r];
        float sg = 1.0f / (1.0f + __expf(-x));
        tf[(size_t)(rowb + r) * COLS + col] = 0.02f + sg * RESR;
      }
    }
  }
}

// ---------------------------------------------------------------- fwd 2048 FFT (radix-2)
static __device__ __forceinline__ void wg_fft2048(float* ar, float* ai,
                                                  float* br, float* bi,
                                                  const float2* tw,
                                                  float** outr, float** outi) {
  float *xr = ar, *xi = ai, *yr = br, *yi = bi;
  int m = 1;
  for (int s = 0; s < 11; ++s) {
    __syncthreads();
#pragma unroll
    for (int it = 0; it < 4; ++it) {
      int t = (int)threadIdx.x + it * 256;
      int jm = t & ~(m - 1);
      float x0r = xr[t], x0i = xi[t];
      float x1r = xr[t + 1024], x1i = xi[t + 1024];
      float2 w = tw[jm];
      float sr = x0r + x1r, si = x0i + x1i;
      float dr = x0r - x1r, di = x0i - x1i;
      float pr = dr * w.x - di * w.y;
      float pi = dr * w.y + di * w.x;
      yr[t + jm] = sr;      yi[t + jm] = si;
      yr[t + jm + m] = pr;  yi[t + jm + m] = pi;
    }
    float* t0 = xr; xr = yr; yr = t0;
    float* t1 = xi; xi = yi; yi = t1;
    m <<= 1;
  }
  __syncthreads();
  *outr = xr; *outi = xi;
}

__global__ __launch_bounds__(256) void fwd_fft_kernel(const float* __restrict__ imp,
                                                      const float* __restrict__ winT,
                                                      const float2* __restrict__ twG,
                                                      float2* __restrict__ cur) {
  __shared__ float b0r[WINSZ], b0i[WINSZ], b1r[WINSZ], b1i[WINSZ];
  __shared__ float2 tw[HALFW];
  int wg = blockIdx.x;
  int b = wg >> 2, f = wg & 3;
  int tid = threadIdx.x;

  for (int i = tid; i < HALFW; i += 256) tw[i] = twG[i];
  for (int w = tid; w < WINSZ; w += 256) {
    int s = f * HALFW + w;
    float v = (s < IMPN) ? imp[(size_t)b * IMPN + s] * winT[w] : 0.0f;
    b0r[w] = v;
    b0i[w] = 0.0f;
  }
  float *rr, *ri;
  wg_fft2048(b0r, b0i, b1r, b1i, tw, &rr, &ri);
  for (int k = tid; k < NCOEF; k += 256)
    cur[(size_t)wg * NCOEF + k] = make_float2(rr[k], ri[k]);
}

// ---------------------------------------------------------------- recurrence
__global__ __launch_bounds__(256) void recur_kernel(const float* __restrict__ tf,
                                                    const float2* __restrict__ cur,
                                                    float2* __restrict__ spec) {
  int id = blockIdx.x * 256 + threadIdx.x;
  if (id >= NB * NCOEF) return;
  int b = id / NCOEF;
  int k = id - b * NCOEF;

  float g = 3.14159265358979323846f * (float)k / 1024.0f;
  float sg, cg;
  sincosf(g, &sg, &cg);
  bool herm = (k == 0) || (k == HALFW);

  const float4* tf4 = (const float4*)(tf + (size_t)b * COLS + (size_t)k * NFR);
  const float2* curb = cur + (size_t)b * 4 * NCOEF + k;
  float2* specb = spec + (size_t)b * NFR * NCOEF + k;

  float pre = 0.0f, pim = 0.0f;
#pragma unroll 2
  for (int f4 = 0; f4 < NFR / 4; ++f4) {
    float4 tv = tf4[f4];
    float tfs[4] = {tv.x, tv.y, tv.z, tv.w};
#pragma unroll
    for (int u = 0; u < 4; ++u) {
      int f = 4 * f4 + u;
      float tfv = tfs[u];
      float cr = 0.0f, ci = 0.0f;
      if (f < 4) {
        float2 cv = curb[(size_t)f * NCOEF];
        cr = cv.x; ci = cv.y;
      }
      float ire = herm ? 0.0f : pim;
      float rre = fmaf(pre, cg, ire * sg);
      float rim = -fmaf(pre, sg, ire * cg);
      float sre = (cr + rre) * tfv;
      float sim = (ci + rim) * tfv;
      specb[(size_t)f * NCOEF] = make_float2(sre, sim);
      pre = sre; pim = sim;
    }
  }
}

// ---------------------------------------------------------------- dual irfft + OLA (no atomics)
__global__ __launch_bounds__(256) void inv_fft_ola_kernel(const float2* __restrict__ spec,
                                                          const float* __restrict__ winT,
                                                          const float2* __restrict__ twG,
                                                          float* __restrict__ out) {
  __shared__ float L[8][1024];
  __shared__ float2 twL[256];
  __shared__ float nyq[2];

  int wg = blockIdx.x;
  int b = wg >> 7, jfr = wg & 127;
  int tid = threadIdx.x;

  if (tid < 256) twL[tid] = twG[2 * tid];

  const float2* spA = spec + ((size_t)b * NFR + jfr) * NCOEF;
  const float2* spB = spec + ((size_t)b * NFR + (jfr > 0 ? jfr - 1 : 0)) * NCOEF;
#pragma unroll
  for (int it = 0; it < 4; ++it) {
    int k = tid + it * 256;
    float2 v = spA[k];
    float2 u = spB[k];
    if (k == 0) { v.y = 0.0f; u.y = 0.0f; }
    int pk = PHYS(k);
    L[4][pk] = v.x; L[5][pk] = v.y;
    L[6][pk] = u.x; L[7][pk] = u.y;
  }
  if (tid == 0) {
    nyq[0] = spA[HALFW].x;
    nyq[1] = spB[HALFW].x;
  }
  __syncthreads();

#pragma unroll
  for (int it = 0; it < 4; ++it) {
    int j = tid + it * 256;
    float2 tg = twG[j];
    float c = tg.x, sn = -tg.y;
    int pj = PHYS(j);
    int pm = PHYS((HALFW - j) & 1023);
#pragma unroll
    for (int q = 0; q < 2; ++q) {
      float xjr = L[4 + 2 * q][pj], xji = L[5 + 2 * q][pj];
      float xmr, xmi;
      if (j == 0) { xmr = nyq[q]; xmi = 0.0f; }
      else        { xmr = L[4 + 2 * q][pm]; xmi = L[5 + 2 * q][pm]; }
      float Xer = 0.5f * (xjr + xmr), Xei = 0.5f * (xji - xmi);
      float Xpr = 0.5f * (xjr - xmr), Xpi = 0.5f * (xji + xmi);
      float Xor_ = Xpr * c - Xpi * sn;
      float Xoi_ = Xpr * sn + Xpi * c;
      L[0 + 2 * q][pj] = Xer - Xoi_;
      L[1 + 2 * q][pj] = -(Xei + Xor_);
    }
  }

  int t = tid;
#pragma unroll
  for (int st = 0; st < 5; ++st) {
    __syncthreads();
    int s2 = 2 * st;
    int s = 1 << s2;
    int q = t & (s - 1);
    int j = t & ~(s - 1);
    float2 w1 = twL[j];
    float w1x = w1.x, w1y = w1.y;
    float w2x = w1x * w1x - w1y * w1y, w2y = 2.0f * w1x * w1y;
    float w3x = w2x * w1x - w2y * w1y, w3y = w2x * w1y + w2y * w1x;
    int i0 = PHYS(t), i1 = PHYS(t + 256), i2 = PHYS(t + 512), i3 = PHYS(t + 768);
    int wb = (j << 2) + q;
    int o0 = PHYS(wb), o1 = PHYS(wb + s), o2 = PHYS(wb + 2 * s), o3 = PHYS(wb + 3 * s);
    const float* xr;
    const float* xi;
    float* yr;
    float* yi;
#pragma unroll
    for (int qq = 0; qq < 2; ++qq) {
      if (st & 1) { xr = L[4 + 2 * qq]; xi = L[5 + 2 * qq]; yr = L[0 + 2 * qq]; yi = L[1 + 2 * qq]; }
      else        { xr = L[0 + 2 * qq]; xi = L[1 + 2 * qq]; yr = L[4 + 2 * qq]; yi = L[5 + 2 * qq]; }
      float ar_ = xr[i0], ai_ = xi[i0];
      float br_ = xr[i1], bi_ = xi[i1];
      float cr_ = xr[i2], ci_ = xi[i2];
      float dr_ = xr[i3], di_ = xi[i3];
      float apcr = ar_ + cr_, apci = ai_ + ci_;
      float amcr = ar_ - cr_, amci = ai_ - ci_;
      float bpdr = br_ + dr_, bpdi = bi_ + di_;
      float bmdr = br_ - dr_, bmdi = bi_ - di_;
      yr[o0] = apcr + bpdr;             yi[o0] = apci + bpdi;
      float t1r = amcr + bmdi, t1i = amci - bmdr;
      yr[o1] = t1r * w1x - t1i * w1y;   yi[o1] = t1r * w1y + t1i * w1x;
      float t2r = apcr - bpdr, t2i = apci - bpdi;
      yr[o2] = t2r * w2x - t2i * w2y;   yi[o2] = t2r * w2y + t2i * w2x;
      float t3r = amcr - bmdi, t3i = amci + bmdr;
      yr[o3] = t3r * w3x - t3i * w3y;   yi[o3] = t3r * w3y + t3i * w3x;
    }
  }
  __syncthreads();

  const float scale = 1.0f / 1024.0f;
  const float sc2 = (jfr > 0) ? scale : 0.0f;
  float2* ob = (float2*)(out + (size_t)b * NSAMP + (size_t)jfr * 1024);
  const float2* w2p = (const float2*)winT;
#pragma unroll
  for (int it = 0; it < 2; ++it) {
    int mI = tid + it * 256;
    float2 wva = w2p[mI];
    float2 wvb = w2p[mI + 512];
    int pa = PHYS(mI), pb = PHYS(mI + 512);
    float e =  L[4][pa] * scale * wva.x + L[6][pb] * sc2 * wvb.x;
    float o = -L[5][pa] * scale * wva.y - L[7][pb] * sc2 * wvb.y;
    ob[mI] = make_float2(e, o);
  }
}

// ---------------------------------------------------------------- launch
extern "C" void kernel_launch(void* const* d_in, const int* in_sizes, int n_in,
                              void* d_out, int out_size, void* d_ws, size_t ws_size,
                              hipStream_t stream) {
  const float* z    = (const float*)d_in[0];
  const float* imp  = (const float*)d_in[1];
  const float* W    = (const float*)d_in[2];
  const float* bias = (const float*)d_in[3];

  float* ws = (float*)d_ws;
  float*  tf   = ws + TF_OFF;
  float2* cur  = (float2*)(ws + CUR_OFF);
  float2* spec = (float2*)(ws + SPEC_OFF);
  float*  winT = ws + WINT_OFF;
  float2* twG  = (float2*)(ws + TW_OFF);
  float*  out  = (float*)d_out;

  init_tables<<<8, 256, 0, stream>>>(winT, twG);
  tf_gemm_mfma<<<COLS / 128, 256, 0, stream>>>(z, W, bias, tf);
  fwd_fft_kernel<<<NB * 4, 256, 0, stream>>>(imp, winT, twG, cur);
  recur_kernel<<<(NB * NCOEF + 255) / 256, 256, 0, stream>>>(tf, cur, spec);
  inv_fft_ola_kernel<<<NB * NFR, 256, 0, stream>>>(spec, winT, twG, out);
}